// Round 9
// baseline (53.907 us; speedup 1.0000x reference)
//
#include <hip/hip_runtime.h>
#include <math.h>

#define LOG2E 1.4426950408889634f
#define NSLOT 512          // LDS window: atoms [key_base, key_base+512)
#define EPT   16           // edges per thread
#define EPB   (256 * EPT)  // 4096 edges per block

// Fully fused ZBL repulsion, EPT=16 max-MLP variant.
// Structure identical to R7 (verified absmax 64): consts recomputed
// uniformly; i-side za window staged in LDS (idx_i sorted; guarded global
// fallback otherwise); j-side gathers z[j]; in-register run merge -> LDS
// atomics -> per-block sweep with i-factor (0.5*z_i*amask_i) folded in.
// This round: 16 edges/thread, ~40 VMEM issued flat per thread, no
// occupancy constraint — discriminates latency-exposure vs L2-request floor.
__global__ __launch_bounds__(256) void zbl_fused_kernel(
    const float* __restrict__ z, const float* __restrict__ amask,
    const float* __restrict__ disp, const int* __restrict__ idx_i,
    const int* __restrict__ idx_j, const float* __restrict__ bmask,
    const float* __restrict__ a_coef, const float* __restrict__ a_exp,
    const float* __restrict__ phi_c, const float* __restrict__ phi_e,
    float* __restrict__ out, int n_edges, int n_atoms) {
  __shared__ float za_s[NSLOT];
  __shared__ float acc[NSLOT];
  const int t = threadIdx.x;
  const long bb = (long)blockIdx.x * EPB;
  const long Q = (long)blockIdx.x * 256 + t;  // global thread id
  const long e0 = Q * (long)EPT;

  // ---- uniform scalar constants (all-lane redundant, cheap)
  const float ae = fabsf(a_exp[0]);
  const float inv_a = 1.0f / fabsf(a_coef[0]);
  float cc0 = fabsf(phi_c[0]), cc1 = fabsf(phi_c[1]);
  float cc2 = fabsf(phi_c[2]), cc3 = fabsf(phi_c[3]);
  {
    float mx = fmaxf(fmaxf(cc0, cc1), fmaxf(cc2, cc3));
    cc0 = expf(cc0 - mx); cc1 = expf(cc1 - mx);
    cc2 = expf(cc2 - mx); cc3 = expf(cc3 - mx);
    float inv_s = 1.0f / (cc0 + cc1 + cc2 + cc3);
    cc0 *= inv_s; cc1 *= inv_s; cc2 *= inv_s; cc3 *= inv_s;
  }
  float q0 = fabsf(phi_e[0]) * LOG2E, q1 = fabsf(phi_e[1]) * LOG2E;
  float q2 = fabsf(phi_e[2]) * LOG2E, q3 = fabsf(phi_e[3]) * LOG2E;
  const float emin = fminf(fminf(q0, q1), fminf(q2, q3));
  // min term gets dd == 0 -> exp2(0) == 1 exactly (matches reference quirk:
  // max_log = -e_min*arg since arg >= 0; shift never added back).
  const float dd0 = (q0 - emin) * inv_a, dd1 = (q1 - emin) * inv_a;
  const float dd2 = (q2 - emin) * inv_a, dd3 = (q3 - emin) * inv_a;

  // ---- phase 1: issue ALL global loads as one flat batch ----
  const int key_base = idx_i[bb];  // uniform broadcast load
  const int a0 = min(key_base + t, n_atoms - 1);
  const int a1 = min(key_base + t + 256, n_atoms - 1);
  const float zw0 = z[a0], zw1 = z[a1];      // window stage (coalesced)
  const float am0 = amask[a0], am1 = amask[a1];

  int kk[EPT];
  float dx[EPT], dy[EPT], dz[EPT], bm[EPT], zj[EPT];
  #pragma unroll
  for (int m = 0; m < EPT; ++m) { kk[m] = -1; dx[m] = dy[m] = dz[m] = bm[m] = 0.f; zj[m] = 1.f; }

  if (e0 + (EPT - 1) < (long)n_edges) {
    int4 I0 = ((const int4*)idx_i)[4 * Q + 0];
    int4 I1 = ((const int4*)idx_i)[4 * Q + 1];
    int4 I2 = ((const int4*)idx_i)[4 * Q + 2];
    int4 I3 = ((const int4*)idx_i)[4 * Q + 3];
    int4 J0 = ((const int4*)idx_j)[4 * Q + 0];
    int4 J1 = ((const int4*)idx_j)[4 * Q + 1];
    int4 J2 = ((const int4*)idx_j)[4 * Q + 2];
    int4 J3 = ((const int4*)idx_j)[4 * Q + 3];
    const float4* d4 = (const float4*)disp;
    float4 D0 = d4[12 * Q + 0],  D1 = d4[12 * Q + 1],  D2 = d4[12 * Q + 2];
    float4 D3 = d4[12 * Q + 3],  D4 = d4[12 * Q + 4],  D5 = d4[12 * Q + 5];
    float4 D6 = d4[12 * Q + 6],  D7 = d4[12 * Q + 7],  D8 = d4[12 * Q + 8];
    float4 D9 = d4[12 * Q + 9],  D10 = d4[12 * Q + 10], D11 = d4[12 * Q + 11];
    float4 B0 = ((const float4*)bmask)[4 * Q + 0];
    float4 B1 = ((const float4*)bmask)[4 * Q + 1];
    float4 B2 = ((const float4*)bmask)[4 * Q + 2];
    float4 B3 = ((const float4*)bmask)[4 * Q + 3];
    // j-gathers (4B each), all independent
    zj[0]  = z[J0.x]; zj[1]  = z[J0.y]; zj[2]  = z[J0.z]; zj[3]  = z[J0.w];
    zj[4]  = z[J1.x]; zj[5]  = z[J1.y]; zj[6]  = z[J1.z]; zj[7]  = z[J1.w];
    zj[8]  = z[J2.x]; zj[9]  = z[J2.y]; zj[10] = z[J2.z]; zj[11] = z[J2.w];
    zj[12] = z[J3.x]; zj[13] = z[J3.y]; zj[14] = z[J3.z]; zj[15] = z[J3.w];
    kk[0]  = I0.x; kk[1]  = I0.y; kk[2]  = I0.z; kk[3]  = I0.w;
    kk[4]  = I1.x; kk[5]  = I1.y; kk[6]  = I1.z; kk[7]  = I1.w;
    kk[8]  = I2.x; kk[9]  = I2.y; kk[10] = I2.z; kk[11] = I2.w;
    kk[12] = I3.x; kk[13] = I3.y; kk[14] = I3.z; kk[15] = I3.w;
    dx[0]  = D0.x;  dy[0]  = D0.y;  dz[0]  = D0.z;
    dx[1]  = D0.w;  dy[1]  = D1.x;  dz[1]  = D1.y;
    dx[2]  = D1.z;  dy[2]  = D1.w;  dz[2]  = D2.x;
    dx[3]  = D2.y;  dy[3]  = D2.z;  dz[3]  = D2.w;
    dx[4]  = D3.x;  dy[4]  = D3.y;  dz[4]  = D3.z;
    dx[5]  = D3.w;  dy[5]  = D4.x;  dz[5]  = D4.y;
    dx[6]  = D4.z;  dy[6]  = D4.w;  dz[6]  = D5.x;
    dx[7]  = D5.y;  dy[7]  = D5.z;  dz[7]  = D5.w;
    dx[8]  = D6.x;  dy[8]  = D6.y;  dz[8]  = D6.z;
    dx[9]  = D6.w;  dy[9]  = D7.x;  dz[9]  = D7.y;
    dx[10] = D7.z;  dy[10] = D7.w;  dz[10] = D8.x;
    dx[11] = D8.y;  dy[11] = D8.z;  dz[11] = D8.w;
    dx[12] = D9.x;  dy[12] = D9.y;  dz[12] = D9.z;
    dx[13] = D9.w;  dy[13] = D10.x; dz[13] = D10.y;
    dx[14] = D10.z; dy[14] = D10.w; dz[14] = D11.x;
    dx[15] = D11.y; dy[15] = D11.z; dz[15] = D11.w;
    bm[0]  = B0.x; bm[1]  = B0.y; bm[2]  = B0.z; bm[3]  = B0.w;
    bm[4]  = B1.x; bm[5]  = B1.y; bm[6]  = B1.z; bm[7]  = B1.w;
    bm[8]  = B2.x; bm[9]  = B2.y; bm[10] = B2.z; bm[11] = B2.w;
    bm[12] = B3.x; bm[13] = B3.y; bm[14] = B3.z; bm[15] = B3.w;
  } else {
    #pragma unroll
    for (int m = 0; m < EPT; ++m) {
      const long e = e0 + m;
      if (e < (long)n_edges) {
        kk[m] = idx_i[e];
        zj[m] = z[idx_j[e]];
        dx[m] = disp[3 * e]; dy[m] = disp[3 * e + 1]; dz[m] = disp[3 * e + 2];
        bm[m] = bmask[e];
      }
    }
  }

  // ---- LDS stage: za window + acc zero ----
  acc[t] = 0.0f;
  acc[t + 256] = 0.0f;
  za_s[t] = __builtin_amdgcn_exp2f(ae * __builtin_amdgcn_logf(zw0));
  za_s[t + 256] = __builtin_amdgcn_exp2f(ae * __builtin_amdgcn_logf(zw1));
  const float fi0 = 0.5f * zw0 * am0;  // sweep factors (i-side, deferred)
  const float fi1 = 0.5f * zw1 * am1;
  __syncthreads();

  // ---- phase 2: per-edge values (pure ALU + LDS broadcast reads) ----
  float vv[EPT];
  #pragma unroll
  for (int m = 0; m < EPT; ++m) {
    float za_i;
    {
      int s = kk[m] - key_base;
      if ((unsigned)s < (unsigned)NSLOT) za_i = za_s[s];
      else if (kk[m] >= 0)  // out-of-window fallback (unsorted pathological)
        za_i = __builtin_amdgcn_exp2f(ae * __builtin_amdgcn_logf(z[kk[m]]));
      else za_i = 0.0f;
    }
    float n2 = fmaxf(dx[m] * dx[m] + dy[m] * dy[m] + dz[m] * dz[m], 1e-20f);
    float r = __builtin_amdgcn_rsqf(n2);  // 1/d
    float d = n2 * r;                     // d = sqrt(n2)
    float x = 5.0f - d;
    float poly = ((6.0f * x - 15.0f) * x + 10.0f) * x * x * x;
    float sw = (d < 4.0f) ? 1.0f : ((d >= 5.0f) ? 0.0f : poly);
    float zaj = __builtin_amdgcn_exp2f(ae * __builtin_amdgcn_logf(zj[m]));
    float qq = d * fmaxf(za_i + zaj, 1e-10f);
    float phi = cc0 * __builtin_amdgcn_exp2f(-dd0 * qq)
              + cc1 * __builtin_amdgcn_exp2f(-dd1 * qq)
              + cc2 * __builtin_amdgcn_exp2f(-dd2 * qq)
              + cc3 * __builtin_amdgcn_exp2f(-dd3 * qq);
    // i-factor (0.5*z_i*amask_i) deferred to sweep
    vv[m] = zj[m] * r * fmaxf(phi, 1e-30f) * fmaxf(sw, 1e-30f) * bm[m];
  }

  auto flush = [&](int key, float s) {
    if (key < 0) return;
    int slot = key - key_base;
    if ((unsigned)slot < (unsigned)NSLOT) {
      atomicAdd(&acc[slot], s);
    } else {  // rare fallback: apply i-factor directly
      atomicAdd(&out[key], s * 0.5f * z[key] * amask[key]);
    }
  };

  // ---- in-register merge of equal-adjacent keys ----
  {
    int cur = kk[0];
    float s = vv[0];
    #pragma unroll
    for (int m = 1; m < EPT; ++m) {
      if (kk[m] == cur) s += vv[m];
      else { flush(cur, s); cur = kk[m]; s = vv[m]; }
    }
    flush(cur, s);
  }

  __syncthreads();  // all LDS accumulation done

  // ---- sweep: one global atomic per touched atom ----
  {
    float val = acc[t];
    if (val != 0.0f) atomicAdd(&out[key_base + t], val * fi0);
    val = acc[t + 256];
    if (val != 0.0f) atomicAdd(&out[key_base + t + 256], val * fi1);
  }
}

extern "C" void kernel_launch(void* const* d_in, const int* in_sizes, int n_in,
                              void* d_out, int out_size, void* d_ws,
                              size_t ws_size, hipStream_t stream) {
  const float* atomic_numbers = (const float*)d_in[0];
  const float* disp           = (const float*)d_in[1];
  const int*   idx_i          = (const int*)d_in[2];
  const int*   idx_j          = (const int*)d_in[3];
  const float* atom_mask      = (const float*)d_in[4];
  // d_in[5] = batch_segments (unused), d_in[7] = batch_size (unused)
  const float* bmask          = (const float*)d_in[6];
  const float* a_coef         = (const float*)d_in[8];
  const float* a_exp          = (const float*)d_in[9];
  const float* phi_c          = (const float*)d_in[10];
  const float* phi_e          = (const float*)d_in[11];

  int n_atoms = in_sizes[0];
  int n_edges = in_sizes[2];

  float* out = (float*)d_out;

  hipMemsetAsync(out, 0, (size_t)out_size * sizeof(float), stream);

  int edge_blocks = (int)(((long)n_edges + EPB - 1) / EPB);
  zbl_fused_kernel<<<edge_blocks, 256, 0, stream>>>(
      atomic_numbers, atom_mask, disp, idx_i, idx_j, bmask, a_coef, a_exp,
      phi_c, phi_e, out, n_edges, n_atoms);
}